// Round 1
// baseline (296.179 us; speedup 1.0000x reference)
//
#include <hip/hip_runtime.h>
#include <hip/hip_bf16.h>

// MinGRU forward: z=sigmoid(xWz^T), h~=xWh^T, a=1-z+1e-8, b=z*h~, scan h=a*h+b.
// B=4 T=4096 D=1024. GEMM: bf16 MFMA 16x16x32, dual-accumulate (Wz+Wh share A frag).
// Scan: 3-pass chunked (chunk=64): per-chunk affine compose, wave64 shuffle scan
// over chunks, then apply. a stored bf16 in ws (32MB), b fp32 in d_out.

typedef __bf16 bf16x8 __attribute__((ext_vector_type(8)));
typedef float  f32x4  __attribute__((ext_vector_type(4)));

#define BSZ 4
#define TSZ 4096
#define DSZ 1024
#define MSZ (BSZ*TSZ)      // 16384 rows
#define CH  64             // scan chunk length
#define NC  (TSZ/CH)       // 64 chunks per sequence

// ---------------- GEMM + gate epilogue ----------------
// block tile 128(M) x 128(N), BK=32; 256 threads = 4 waves in 2x2, each wave 64x64.
__global__ __launch_bounds__(256, 2) void gemm_gate_kernel(
    const float* __restrict__ X,  const float* __restrict__ Wz,
    const float* __restrict__ bz, const float* __restrict__ Wh,
    const float* __restrict__ bh,
    __bf16* __restrict__ a_ws, float* __restrict__ b_out)
{
  // XOR-swizzled LDS (stride 32 bf16 = 64B/row; phys chunk = kc ^ ((r>>1)&3))
  // -> 2-way bank aliasing on both ds_write_b128 and ds_read_b128 (free, m136).
  __shared__ __align__(16) __bf16 As [128*32];
  __shared__ __align__(16) __bf16 Bzs[128*32];
  __shared__ __align__(16) __bf16 Bhs[128*32];

  const int tid  = threadIdx.x;
  const int M0   = blockIdx.x * 128;
  const int N0   = blockIdx.y * 128;
  const int lane = tid & 63;
  const int wv   = tid >> 6;
  const int wM   = (wv >> 1) * 64;
  const int wN   = (wv & 1) * 64;
  const int lr   = lane & 15;   // row-within-16 for A/B operand frags
  const int q    = lane >> 4;   // k-chunk selector (8 bf16 per chunk)

  f32x4 accz[4][4] = {};
  f32x4 acch[4][4] = {};

  for (int k0 = 0; k0 < DSZ; k0 += 32) {
    __syncthreads();
    // stage 3 tiles of 128x32 bf16; each thread: 2 chunks of 8 elems per tile
    #pragma unroll
    for (int cc = 0; cc < 2; ++cc) {
      const int c  = tid + cc*256;       // 0..511
      const int r  = c >> 2;
      const int kc = c & 3;
      const int lofs = r*32 + ((kc ^ ((r>>1)&3)) << 3);
      {
        const float* g = X + (size_t)(M0 + r)*DSZ + k0 + kc*8;
        float4 v0 = *(const float4*)g;
        float4 v1 = *(const float4*)(g + 4);
        bf16x8 p0; p0[0]=(__bf16)v0.x; p0[1]=(__bf16)v0.y; p0[2]=(__bf16)v0.z; p0[3]=(__bf16)v0.w;
                   p0[4]=(__bf16)v1.x; p0[5]=(__bf16)v1.y; p0[6]=(__bf16)v1.z; p0[7]=(__bf16)v1.w;
        *(bf16x8*)(As + lofs) = p0;
      }
      {
        const float* g = Wz + (size_t)(N0 + r)*DSZ + k0 + kc*8;
        float4 v0 = *(const float4*)g;
        float4 v1 = *(const float4*)(g + 4);
        bf16x8 p1; p1[0]=(__bf16)v0.x; p1[1]=(__bf16)v0.y; p1[2]=(__bf16)v0.z; p1[3]=(__bf16)v0.w;
                   p1[4]=(__bf16)v1.x; p1[5]=(__bf16)v1.y; p1[6]=(__bf16)v1.z; p1[7]=(__bf16)v1.w;
        *(bf16x8*)(Bzs + lofs) = p1;
      }
      {
        const float* g = Wh + (size_t)(N0 + r)*DSZ + k0 + kc*8;
        float4 v0 = *(const float4*)g;
        float4 v1 = *(const float4*)(g + 4);
        bf16x8 p2; p2[0]=(__bf16)v0.x; p2[1]=(__bf16)v0.y; p2[2]=(__bf16)v0.z; p2[3]=(__bf16)v0.w;
                   p2[4]=(__bf16)v1.x; p2[5]=(__bf16)v1.y; p2[6]=(__bf16)v1.z; p2[7]=(__bf16)v1.w;
        *(bf16x8*)(Bhs + lofs) = p2;
      }
    }
    __syncthreads();

    // A operand: lane holds A[m=l&15][k=(l>>4)*8+j]; B operand: B[k][n=l&15]=W[n][k]
    bf16x8 af[4];
    #pragma unroll
    for (int i = 0; i < 4; ++i) {
      const int m = wM + i*16 + lr;
      af[i] = *(const bf16x8*)(As + m*32 + ((q ^ ((m>>1)&3)) << 3));
    }
    #pragma unroll
    for (int j = 0; j < 4; ++j) {
      const int e   = wN + j*16 + lr;
      const int off = e*32 + ((q ^ ((e>>1)&3)) << 3);
      bf16x8 bz8 = *(const bf16x8*)(Bzs + off);
      bf16x8 bh8 = *(const bf16x8*)(Bhs + off);
      #pragma unroll
      for (int i = 0; i < 4; ++i) {
        accz[j][i] = __builtin_amdgcn_mfma_f32_16x16x32_bf16(af[i], bz8, accz[j][i], 0, 0, 0);
        acch[j][i] = __builtin_amdgcn_mfma_f32_16x16x32_bf16(af[i], bh8, acch[j][i], 0, 0, 0);
      }
    }
  }

  // epilogue: C/D layout col=lane&15, row=(lane>>4)*4+reg (verified m89/m91)
  #pragma unroll
  for (int j = 0; j < 4; ++j) {
    const int e = N0 + wN + j*16 + lr;
    const float bzv = bz[e];
    const float bhv = bh[e];
    #pragma unroll
    for (int i = 0; i < 4; ++i) {
      const int mbase = M0 + wM + i*16 + q*4;
      #pragma unroll
      for (int r = 0; r < 4; ++r) {
        const size_t idx = (size_t)(mbase + r)*DSZ + e;
        const float pz = accz[j][i][r] + bzv;
        const float ph = acch[j][i][r] + bhv;
        const float ex = __expf(-pz);
        const float z  = 1.0f / (1.0f + ex);
        a_ws[idx]  = (__bf16)fmaf(ex, z, 1e-8f);  // (1-z) + 1e-8
        b_out[idx] = z * ph;                       // b term, fp32 in d_out
      }
    }
  }
}

// ---------------- scan pass 1: per-chunk affine composition ----------------
// thread = (b, chunk, d); grid: B*NC*(D/256) = 1024 blocks x 256
__global__ void scan_pass1_kernel(const __bf16* __restrict__ a_ws,
                                  const float* __restrict__ b_out,
                                  float* __restrict__ Aprod,
                                  float* __restrict__ Bcomp)
{
  const int tid  = threadIdx.x;
  const int bc   = blockIdx.x >> 2;                 // b*NC + c  (0..255)
  const int d    = ((blockIdx.x & 3) << 8) + tid;
  const int base = bc * (CH*DSZ) + d;
  float A = 1.0f, Bv = 0.0f;
  #pragma unroll 8
  for (int t = 0; t < CH; ++t) {
    const float a = (float)a_ws[base + t*DSZ];
    const float b = b_out[base + t*DSZ];
    Bv = fmaf(a, Bv, b);
    A *= a;
  }
  const int cidx = bc*DSZ + d;
  Aprod[cidx] = A;
  Bcomp[cidx] = Bv;
}

// ---------------- scan pass 2: wave64 shuffle scan over the 64 chunks ----------------
// one wave per (b,d) channel; lane = chunk index. 4096 waves -> 1024 blocks of 256.
__global__ void scan_pass2_kernel(const float* __restrict__ Aprod,
                                  const float* __restrict__ Bcomp,
                                  float* __restrict__ Hstart)
{
  const int lane = threadIdx.x & 63;
  const int wave = (blockIdx.x * 256 + threadIdx.x) >> 6;  // 0..4095
  const int b = wave >> 10;
  const int d = wave & 1023;
  const int idx = (b*NC + lane)*DSZ + d;
  float A  = Aprod[idx];
  float Bv = Bcomp[idx];
  // inclusive Hillis-Steele affine scan: new = own o prev
  #pragma unroll
  for (int s = 1; s < 64; s <<= 1) {
    const float Ap = __shfl_up(A,  s, 64);
    const float Bp = __shfl_up(Bv, s, 64);
    if (lane >= s) { Bv = fmaf(A, Bp, Bv); A *= Ap; }
  }
  float Hs = __shfl_up(Bv, 1, 64);  // exclusive: h at chunk start (h0 = 0)
  if (lane == 0) Hs = 0.0f;
  Hstart[idx] = Hs;
}

// ---------------- scan pass 3: apply within chunk, write h ----------------
__global__ void scan_pass3_kernel(const __bf16* __restrict__ a_ws,
                                  const float* __restrict__ Hstart,
                                  float* __restrict__ out)
{
  const int tid  = threadIdx.x;
  const int bc   = blockIdx.x >> 2;
  const int d    = ((blockIdx.x & 3) << 8) + tid;
  const int base = bc * (CH*DSZ) + d;
  float h = Hstart[bc*DSZ + d];
  #pragma unroll 8
  for (int t = 0; t < CH; ++t) {
    const float a = (float)a_ws[base + t*DSZ];
    const float b = out[base + t*DSZ];   // b term staged in d_out
    h = fmaf(a, h, b);
    out[base + t*DSZ] = h;
  }
}

extern "C" void kernel_launch(void* const* d_in, const int* in_sizes, int n_in,
                              void* d_out, int out_size, void* d_ws, size_t ws_size,
                              hipStream_t stream)
{
  const float* x  = (const float*)d_in[0];
  const float* Wz = (const float*)d_in[1];
  const float* bz = (const float*)d_in[2];
  const float* Wh = (const float*)d_in[3];
  const float* bh = (const float*)d_in[4];
  float* out = (float*)d_out;

  // ws layout: a (bf16, 32MB) | Aprod | Bcomp | Hstart (each B*NC*D fp32 = 1MB)
  __bf16* a_ws = (__bf16*)d_ws;
  char*  p      = (char*)d_ws + (size_t)MSZ * DSZ * 2;
  float* Aprod  = (float*)p;
  float* Bcomp  = Aprod + BSZ*NC*DSZ;
  float* Hstart = Bcomp + BSZ*NC*DSZ;

  gemm_gate_kernel<<<dim3(MSZ/128, DSZ/128), 256, 0, stream>>>(x, Wz, bz, Wh, bh, a_ws, out);
  scan_pass1_kernel<<<BSZ*NC*4, 256, 0, stream>>>(a_ws, out, Aprod, Bcomp);
  scan_pass2_kernel<<<(BSZ*DSZ)/4, 256, 0, stream>>>(Aprod, Bcomp, Hstart);
  scan_pass3_kernel<<<BSZ*NC*4, 256, 0, stream>>>(a_ws, Hstart, out);
}

// Round 2
// 255.552 us; speedup vs baseline: 1.1590x; 1.1590x over previous
//
#include <hip/hip_runtime.h>
#include <hip/hip_bf16.h>

// MinGRU forward: z=sigmoid(xWz^T), h~=xWh^T, a=1-z+1e-8, b=z*h~, scan h=a*h+b.
// B=4 T=4096 D=1024.
// R2: pre-convert X/Wz/Wh -> bf16 in fragment-tiled layout, GEMM stages via
// __builtin_amdgcn_global_load_lds width=16 (m97 structure), dual-accumulate.
// Scan: CH=32 chunks, 4-wide vectorized passes; pass2 = wave64 shuffle scan,
// 2 chunks per lane.

typedef __bf16 bf16x8 __attribute__((ext_vector_type(8)));
typedef __bf16 bf16x4 __attribute__((ext_vector_type(4)));
typedef float  f32x4  __attribute__((ext_vector_type(4)));

#define BSZ 4
#define TSZ 4096
#define DSZ 1024
#define MSZ (BSZ*TSZ)      // 16384 rows
#define CH  32             // scan chunk length
#define NC  (TSZ/CH)       // 128 chunks per sequence

__device__ __forceinline__ void gload_lds16(const __bf16* g, __bf16* l) {
  __builtin_amdgcn_global_load_lds(
      (const __attribute__((address_space(1))) void*)g,
      (__attribute__((address_space(3))) void*)l, 16, 0, 0);
}

// ---------------- conversion: fp32 row-major -> bf16 fragment-tiled ----------------
// tiled layout: [rowblk][kblk:32][i:8][l:64][j:8] where
//   row = rowblk*128 + i*16 + (l&15), k = kblk*32 + (l>>4)*8 + j
// One thread handles one (l, j-octet): 8 outputs, 2 float4 reads, 1 bf16x8 write.
__global__ void convert_tile_kernel(const float* __restrict__ X,
                                    const float* __restrict__ Wz,
                                    const float* __restrict__ Wh,
                                    __bf16* __restrict__ Xc,
                                    __bf16* __restrict__ Wzc,
                                    __bf16* __restrict__ Whc)
{
  const int bx = blockIdx.x;
  const float* src; __bf16* dst; int gid;
  if (bx < 8192)      { src = X;  dst = Xc;  gid =  bx        *256 + threadIdx.x; }
  else if (bx < 8704) { src = Wz; dst = Wzc; gid = (bx - 8192)*256 + threadIdx.x; }
  else                { src = Wh; dst = Whc; gid = (bx - 8704)*256 + threadIdx.x; }
  const int l    = gid & 63;
  const int i    = (gid >> 6) & 7;
  const int kblk = (gid >> 9) & 31;
  const int rblk = gid >> 14;
  const int row  = rblk*128 + i*16 + (l & 15);
  const int col  = kblk*32 + (l >> 4)*8;
  const float* g = src + (size_t)row*DSZ + col;
  float4 v0 = *(const float4*)g;
  float4 v1 = *(const float4*)(g + 4);
  bf16x8 p;
  p[0]=(__bf16)v0.x; p[1]=(__bf16)v0.y; p[2]=(__bf16)v0.z; p[3]=(__bf16)v0.w;
  p[4]=(__bf16)v1.x; p[5]=(__bf16)v1.y; p[6]=(__bf16)v1.z; p[7]=(__bf16)v1.w;
  *(bf16x8*)(dst + (size_t)gid*8) = p;
}

// ---------------- GEMM + gate epilogue ----------------
// block tile 128(M) x 128(N), BK=32; 256 threads = 4 waves in 2x2, each wave 64x64.
// Staging: global_load_lds 16B/lane from the fragment-tiled bf16 arrays; LDS is
// lane-linear so ds_read_b128 at lane*16B is 2-way-alias only (free).
__global__ __launch_bounds__(256, 2) void gemm_gate_kernel(
    const __bf16* __restrict__ Xc,  const __bf16* __restrict__ Wzc,
    const __bf16* __restrict__ Whc,
    const float* __restrict__ bz, const float* __restrict__ bh,
    __bf16* __restrict__ a_ws, float* __restrict__ b_out)
{
  __shared__ __align__(16) __bf16 As [4096];
  __shared__ __align__(16) __bf16 Bzs[4096];
  __shared__ __align__(16) __bf16 Bhs[4096];

  const int tid  = threadIdx.x;
  const int lane = tid & 63;
  const int wv   = tid >> 6;
  const int wM   = (wv >> 1) * 64;
  const int wN   = (wv & 1) * 64;
  const int wMg  = wM >> 4;
  const int wNg  = wN >> 4;
  const int lr   = lane & 15;
  const int q    = lane >> 4;
  const int wbase = wv * 64;           // wave-uniform

  const __bf16* Xb = Xc  + (size_t)blockIdx.x * 32 * 4096;
  const __bf16* Zb = Wzc + (size_t)blockIdx.y * 32 * 4096;
  const __bf16* Hb = Whc + (size_t)blockIdx.y * 32 * 4096;

  f32x4 accz[4][4] = {};
  f32x4 acch[4][4] = {};

  for (int kblk = 0; kblk < 32; ++kblk) {
    __syncthreads();
    const size_t tb = (size_t)kblk * 4096;
    #pragma unroll
    for (int c = 0; c < 2; ++c) {
      const int eo = (c*256 + wbase + lane) * 8;  // per-lane global elem offset
      const int lo = (c*256 + wbase) * 8;         // wave-uniform LDS elem offset
      gload_lds16(Xb + tb + eo, As  + lo);
      gload_lds16(Zb + tb + eo, Bzs + lo);
      gload_lds16(Hb + tb + eo, Bhs + lo);
    }
    __syncthreads();

    bf16x8 af[4];
    #pragma unroll
    for (int i = 0; i < 4; ++i)
      af[i] = *(const bf16x8*)(As + (wMg + i)*512 + lane*8);
    #pragma unroll
    for (int j = 0; j < 4; ++j) {
      bf16x8 bz8 = *(const bf16x8*)(Bzs + (wNg + j)*512 + lane*8);
      bf16x8 bh8 = *(const bf16x8*)(Bhs + (wNg + j)*512 + lane*8);
      #pragma unroll
      for (int i = 0; i < 4; ++i) {
        accz[j][i] = __builtin_amdgcn_mfma_f32_16x16x32_bf16(af[i], bz8, accz[j][i], 0, 0, 0);
        acch[j][i] = __builtin_amdgcn_mfma_f32_16x16x32_bf16(af[i], bh8, acch[j][i], 0, 0, 0);
      }
    }
  }

  // epilogue: C/D layout col=lane&15, row=(lane>>4)*4+reg (verified m89/m91)
  const int M0 = blockIdx.x * 128;
  const int N0 = blockIdx.y * 128;
  #pragma unroll
  for (int j = 0; j < 4; ++j) {
    const int e = N0 + wN + j*16 + lr;
    const float bzv = bz[e];
    const float bhv = bh[e];
    #pragma unroll
    for (int i = 0; i < 4; ++i) {
      const int mbase = M0 + wM + i*16 + q*4;
      #pragma unroll
      for (int r = 0; r < 4; ++r) {
        const size_t idx = (size_t)(mbase + r)*DSZ + e;
        const float pz = accz[j][i][r] + bzv;
        const float ph = acch[j][i][r] + bhv;
        const float ex = __expf(-pz);
        const float z  = 1.0f / (1.0f + ex);
        a_ws[idx]  = (__bf16)fmaf(ex, z, 1e-8f);  // (1-z) + 1e-8
        b_out[idx] = z * ph;                       // b term, fp32 in d_out
      }
    }
  }
}

// ---------------- scan pass 1: per-chunk affine composition (4 d per thread) ----
// grid: B*NC = 512 blocks x 256 threads
__global__ void scan_pass1_kernel(const __bf16* __restrict__ a_ws,
                                  const float* __restrict__ b_out,
                                  float* __restrict__ Aprod,
                                  float* __restrict__ Bcomp)
{
  const int bc   = blockIdx.x;            // b*NC + c
  const int d0   = threadIdx.x * 4;
  const size_t base = (size_t)bc * CH * DSZ + d0;
  float A[4]  = {1.f, 1.f, 1.f, 1.f};
  float Bv[4] = {0.f, 0.f, 0.f, 0.f};
  #pragma unroll 8
  for (int t = 0; t < CH; ++t) {
    bf16x4 a4 = *(const bf16x4*)(a_ws + base + (size_t)t*DSZ);
    float4 b4 = *(const float4*)(b_out + base + (size_t)t*DSZ);
    const float bb[4] = {b4.x, b4.y, b4.z, b4.w};
    #pragma unroll
    for (int c = 0; c < 4; ++c) {
      const float a = (float)a4[c];
      Bv[c] = fmaf(a, Bv[c], bb[c]);
      A[c] *= a;
    }
  }
  const size_t cidx = (size_t)bc*DSZ + d0;
  *(float4*)(Aprod + cidx) = make_float4(A[0], A[1], A[2], A[3]);
  *(float4*)(Bcomp + cidx) = make_float4(Bv[0], Bv[1], Bv[2], Bv[3]);
}

// ---------------- scan pass 2: wave64 shuffle scan, 2 chunks per lane --------
// one wave per (b,d); 4096 waves -> 1024 blocks of 256.
__global__ void scan_pass2_kernel(const float* __restrict__ Aprod,
                                  const float* __restrict__ Bcomp,
                                  float* __restrict__ Hstart)
{
  const int lane = threadIdx.x & 63;
  const int wave = (blockIdx.x * 256 + threadIdx.x) >> 6;  // 0..4095
  const int b = wave >> 10;
  const int d = wave & 1023;
  const size_t i0 = (size_t)(b*NC + 2*lane)*DSZ + d;
  const float A0 = Aprod[i0],       B0 = Bcomp[i0];
  const float A1 = Aprod[i0 + DSZ], B1 = Bcomp[i0 + DSZ];
  float A  = A0 * A1;               // pair compose: chunk 2l then 2l+1
  float Bv = fmaf(A1, B0, B1);
  // inclusive Hillis-Steele affine scan over lane pairs
  #pragma unroll
  for (int s = 1; s < 64; s <<= 1) {
    const float Ap = __shfl_up(A,  s, 64);
    const float Bp = __shfl_up(Bv, s, 64);
    if (lane >= s) { Bv = fmaf(A, Bp, Bv); A *= Ap; }
  }
  float Hp = __shfl_up(Bv, 1, 64);  // exclusive: h at start of chunk 2l
  if (lane == 0) Hp = 0.0f;
  Hstart[i0]       = Hp;
  Hstart[i0 + DSZ] = fmaf(A0, Hp, B0);  // h at start of chunk 2l+1
}

// ---------------- scan pass 3: apply within chunk (4 d per thread) -----------
__global__ void scan_pass3_kernel(const __bf16* __restrict__ a_ws,
                                  const float* __restrict__ Hstart,
                                  float* __restrict__ out)
{
  const int bc   = blockIdx.x;
  const int d0   = threadIdx.x * 4;
  const size_t base = (size_t)bc * CH * DSZ + d0;
  float4 hv = *(const float4*)(Hstart + (size_t)bc*DSZ + d0);
  float h[4] = {hv.x, hv.y, hv.z, hv.w};
  #pragma unroll 8
  for (int t = 0; t < CH; ++t) {
    bf16x4 a4 = *(const bf16x4*)(a_ws + base + (size_t)t*DSZ);
    float4 b4 = *(const float4*)(out + base + (size_t)t*DSZ);
    const float bb[4] = {b4.x, b4.y, b4.z, b4.w};
    #pragma unroll
    for (int c = 0; c < 4; ++c)
      h[c] = fmaf((float)a4[c], h[c], bb[c]);
    *(float4*)(out + base + (size_t)t*DSZ) = make_float4(h[0], h[1], h[2], h[3]);
  }
}

extern "C" void kernel_launch(void* const* d_in, const int* in_sizes, int n_in,
                              void* d_out, int out_size, void* d_ws, size_t ws_size,
                              hipStream_t stream)
{
  const float* x  = (const float*)d_in[0];
  const float* Wz = (const float*)d_in[1];
  const float* bz = (const float*)d_in[2];
  const float* Wh = (const float*)d_in[3];
  const float* bh = (const float*)d_in[4];
  float* out = (float*)d_out;

  // ws layout: Xc (32MB) | Wzc (2MB) | Whc (2MB) | a (32MB) | Aprod|Bcomp|Hstart (2MB each)
  __bf16* Xc   = (__bf16*)d_ws;
  __bf16* Wzc  = Xc  + (size_t)MSZ * DSZ;
  __bf16* Whc  = Wzc + (size_t)DSZ * DSZ;
  __bf16* a_ws = Whc + (size_t)DSZ * DSZ;
  float* Aprod  = (float*)(a_ws + (size_t)MSZ * DSZ);
  float* Bcomp  = Aprod + (size_t)BSZ*NC*DSZ;
  float* Hstart = Bcomp + (size_t)BSZ*NC*DSZ;

  convert_tile_kernel<<<9216, 256, 0, stream>>>(x, Wz, Wh, Xc, Wzc, Whc);
  gemm_gate_kernel<<<dim3(MSZ/128, DSZ/128), 256, 0, stream>>>(Xc, Wzc, Whc, bz, bh, a_ws, out);
  scan_pass1_kernel<<<BSZ*NC, 256, 0, stream>>>(a_ws, out, Aprod, Bcomp);
  scan_pass2_kernel<<<(BSZ*DSZ)/4, 256, 0, stream>>>(Aprod, Bcomp, Hstart);
  scan_pass3_kernel<<<BSZ*NC, 256, 0, stream>>>(a_ws, Hstart, out);
}

// Round 3
// 244.752 us; speedup vs baseline: 1.2101x; 1.0441x over previous
//
#include <hip/hip_runtime.h>
#include <hip/hip_bf16.h>

// MinGRU forward: z=sigmoid(xWz^T), h~=xWh^T, a=1-z+1e-8, b=z*h~, scan h=a*h+b.
// B=4 T=4096 D=1024.
// R3: scan pass1 (per-chunk affine composition) FUSED into the GEMM epilogue via
// cross-lane shuffle scan -- eliminates a 96MB-read dispatch. GEMM: bf16 MFMA
// 16x16x32, dual-accumulate, global_load_lds width=16 staging (m97 structure).
// Remaining scan: pass2 = wave64 shuffle scan over 128 chunks (2/lane),
// pass3 = apply within chunk, 4-wide vectorized.

typedef __bf16 bf16x8 __attribute__((ext_vector_type(8)));
typedef __bf16 bf16x4 __attribute__((ext_vector_type(4)));
typedef float  f32x4  __attribute__((ext_vector_type(4)));

#define BSZ 4
#define TSZ 4096
#define DSZ 1024
#define MSZ (BSZ*TSZ)      // 16384 rows
#define CH  32             // scan chunk length
#define NC  (TSZ/CH)       // 128 chunks per sequence

__device__ __forceinline__ void gload_lds16(const __bf16* g, __bf16* l) {
  __builtin_amdgcn_global_load_lds(
      (const __attribute__((address_space(1))) void*)g,
      (__attribute__((address_space(3))) void*)l, 16, 0, 0);
}

// ---------------- conversion: fp32 row-major -> bf16 fragment-tiled ----------------
// tiled layout: [rowblk][kblk:32][i:8][l:64][j:8] where
//   row = rowblk*128 + i*16 + (l&15), k = kblk*32 + (l>>4)*8 + j
__global__ void convert_tile_kernel(const float* __restrict__ X,
                                    const float* __restrict__ Wz,
                                    const float* __restrict__ Wh,
                                    __bf16* __restrict__ Xc,
                                    __bf16* __restrict__ Wzc,
                                    __bf16* __restrict__ Whc)
{
  const int bx = blockIdx.x;
  const float* src; __bf16* dst; int gid;
  if (bx < 8192)      { src = X;  dst = Xc;  gid =  bx        *256 + threadIdx.x; }
  else if (bx < 8704) { src = Wz; dst = Wzc; gid = (bx - 8192)*256 + threadIdx.x; }
  else                { src = Wh; dst = Whc; gid = (bx - 8704)*256 + threadIdx.x; }
  const int l    = gid & 63;
  const int i    = (gid >> 6) & 7;
  const int kblk = (gid >> 9) & 31;
  const int rblk = gid >> 14;
  const int row  = rblk*128 + i*16 + (l & 15);
  const int col  = kblk*32 + (l >> 4)*8;
  const float* g = src + (size_t)row*DSZ + col;
  float4 v0 = *(const float4*)g;
  float4 v1 = *(const float4*)(g + 4);
  bf16x8 p;
  p[0]=(__bf16)v0.x; p[1]=(__bf16)v0.y; p[2]=(__bf16)v0.z; p[3]=(__bf16)v0.w;
  p[4]=(__bf16)v1.x; p[5]=(__bf16)v1.y; p[6]=(__bf16)v1.z; p[7]=(__bf16)v1.w;
  *(bf16x8*)(dst + (size_t)gid*8) = p;
}

// ---------------- GEMM + gate epilogue + fused per-chunk composition ------------
// block tile 128(M) x 128(N), BK=32; 256 threads = 4 waves in 2x2, each wave 64x64.
__global__ __launch_bounds__(256, 2) void gemm_gate_kernel(
    const __bf16* __restrict__ Xc,  const __bf16* __restrict__ Wzc,
    const __bf16* __restrict__ Whc,
    const float* __restrict__ bz, const float* __restrict__ bh,
    __bf16* __restrict__ a_ws, float* __restrict__ b_out,
    float* __restrict__ Aprod, float* __restrict__ Bcomp)
{
  __shared__ __align__(16) __bf16 As [4096];
  __shared__ __align__(16) __bf16 Bzs[4096];
  __shared__ __align__(16) __bf16 Bhs[4096];

  const int tid  = threadIdx.x;
  const int lane = tid & 63;
  const int wv   = tid >> 6;
  const int wM   = (wv >> 1) * 64;
  const int wN   = (wv & 1) * 64;
  const int wMg  = wM >> 4;
  const int wNg  = wN >> 4;
  const int lr   = lane & 15;
  const int q    = lane >> 4;
  const int wbase = wv * 64;           // wave-uniform

  const __bf16* Xb = Xc  + (size_t)blockIdx.x * 32 * 4096;
  const __bf16* Zb = Wzc + (size_t)blockIdx.y * 32 * 4096;
  const __bf16* Hb = Whc + (size_t)blockIdx.y * 32 * 4096;

  f32x4 accz[4][4] = {};
  f32x4 acch[4][4] = {};

  for (int kblk = 0; kblk < 32; ++kblk) {
    __syncthreads();
    const size_t tb = (size_t)kblk * 4096;
    #pragma unroll
    for (int c = 0; c < 2; ++c) {
      const int eo = (c*256 + wbase + lane) * 8;  // per-lane global elem offset
      const int lo = (c*256 + wbase) * 8;         // wave-uniform LDS elem offset
      gload_lds16(Xb + tb + eo, As  + lo);
      gload_lds16(Zb + tb + eo, Bzs + lo);
      gload_lds16(Hb + tb + eo, Bhs + lo);
    }
    __syncthreads();

    bf16x8 af[4];
    #pragma unroll
    for (int i = 0; i < 4; ++i)
      af[i] = *(const bf16x8*)(As + (wMg + i)*512 + lane*8);
    #pragma unroll
    for (int j = 0; j < 4; ++j) {
      bf16x8 bz8 = *(const bf16x8*)(Bzs + (wNg + j)*512 + lane*8);
      bf16x8 bh8 = *(const bf16x8*)(Bhs + (wNg + j)*512 + lane*8);
      #pragma unroll
      for (int i = 0; i < 4; ++i) {
        accz[j][i] = __builtin_amdgcn_mfma_f32_16x16x32_bf16(af[i], bz8, accz[j][i], 0, 0, 0);
        acch[j][i] = __builtin_amdgcn_mfma_f32_16x16x32_bf16(af[i], bh8, acch[j][i], 0, 0, 0);
      }
    }
  }

  // ---- epilogue: gate + store + fused per-chunk affine composition ----
  // C/D layout col=lane&15, row=(lane>>4)*4+reg (verified m89/m91).
  // Lane's 4 regs of tile i cover rows wM+i*16+q*4 .. +3 (4 consecutive t).
  // Chunk (32 rows) = i-pair {2c,2c+1}; row order within chunk: q inner, i outer.
  const int M0 = blockIdx.x * 128;
  const int N0 = blockIdx.y * 128;
  #pragma unroll
  for (int j = 0; j < 4; ++j) {
    const int e = N0 + wN + j*16 + lr;
    const float bzv = bz[e];
    const float bhv = bh[e];
    float Aseg[4], Bseg[4];
    #pragma unroll
    for (int i = 0; i < 4; ++i) {
      const int mbase = M0 + wM + i*16 + q*4;
      float A = 1.0f, Bv = 0.0f;
      #pragma unroll
      for (int r = 0; r < 4; ++r) {
        const size_t idx = (size_t)(mbase + r)*DSZ + e;
        const float pz = accz[j][i][r] + bzv;
        const float ph = acch[j][i][r] + bhv;
        const float ex = __expf(-pz);
        const float z  = 1.0f / (1.0f + ex);
        const __bf16 abf = (__bf16)fmaf(ex, z, 1e-8f);  // (1-z) + 1e-8
        const float  af  = (float)abf;                   // rounded, matches pass3
        const float  bf  = z * ph;
        a_ws[idx]  = abf;
        b_out[idx] = bf;
        Bv = fmaf(af, Bv, bf);
        A *= af;
      }
      Aseg[i] = A; Bseg[i] = Bv;
    }
    // scan across the 4 q-lanes (stride 16) for each i: lane q ends with
    // composition of segments q'=0..q; q=3 holds the full 16-row composition.
    #pragma unroll
    for (int i = 0; i < 4; ++i) {
      #pragma unroll
      for (int s = 16; s < 64; s <<= 1) {
        const float Ap = __shfl_up(Aseg[i], s, 64);
        const float Bp = __shfl_up(Bseg[i], s, 64);
        if (lane >= s) { Bseg[i] = fmaf(Aseg[i], Bp, Bseg[i]); Aseg[i] *= Ap; }
      }
    }
    if (q == 3) {
      #pragma unroll
      for (int c = 0; c < 2; ++c) {
        // chunk = rows [wM+c*32, wM+c*32+31] = i-segments 2c (earlier) then 2c+1
        const float Ac = Aseg[2*c+1] * Aseg[2*c];
        const float Bc = fmaf(Aseg[2*c+1], Bseg[2*c], Bseg[2*c+1]);
        const int bc = (M0 + wM + c*32) >> 5;   // = b*NC + chunk (NC=128)
        Aprod[(size_t)bc*DSZ + e] = Ac;
        Bcomp[(size_t)bc*DSZ + e] = Bc;
      }
    }
  }
}

// ---------------- scan pass 2: wave64 shuffle scan, 2 chunks per lane --------
// one wave per (b,d); 4096 waves -> 1024 blocks of 256.
__global__ void scan_pass2_kernel(const float* __restrict__ Aprod,
                                  const float* __restrict__ Bcomp,
                                  float* __restrict__ Hstart)
{
  const int lane = threadIdx.x & 63;
  const int wave = (blockIdx.x * 256 + threadIdx.x) >> 6;  // 0..4095
  const int b = wave >> 10;
  const int d = wave & 1023;
  const size_t i0 = (size_t)(b*NC + 2*lane)*DSZ + d;
  const float A0 = Aprod[i0],       B0 = Bcomp[i0];
  const float A1 = Aprod[i0 + DSZ], B1 = Bcomp[i0 + DSZ];
  float A  = A0 * A1;               // pair compose: chunk 2l then 2l+1
  float Bv = fmaf(A1, B0, B1);
  #pragma unroll
  for (int s = 1; s < 64; s <<= 1) {
    const float Ap = __shfl_up(A,  s, 64);
    const float Bp = __shfl_up(Bv, s, 64);
    if (lane >= s) { Bv = fmaf(A, Bp, Bv); A *= Ap; }
  }
  float Hp = __shfl_up(Bv, 1, 64);  // exclusive: h at start of chunk 2l
  if (lane == 0) Hp = 0.0f;
  Hstart[i0]       = Hp;
  Hstart[i0 + DSZ] = fmaf(A0, Hp, B0);  // h at start of chunk 2l+1
}

// ---------------- scan pass 3: apply within chunk (4 d per thread) -----------
__global__ void scan_pass3_kernel(const __bf16* __restrict__ a_ws,
                                  const float* __restrict__ Hstart,
                                  float* __restrict__ out)
{
  const int bc   = blockIdx.x;
  const int d0   = threadIdx.x * 4;
  const size_t base = (size_t)bc * CH * DSZ + d0;
  float4 hv = *(const float4*)(Hstart + (size_t)bc*DSZ + d0);
  float h[4] = {hv.x, hv.y, hv.z, hv.w};
  #pragma unroll 8
  for (int t = 0; t < CH; ++t) {
    bf16x4 a4 = *(const bf16x4*)(a_ws + base + (size_t)t*DSZ);
    float4 b4 = *(const float4*)(out + base + (size_t)t*DSZ);
    const float bb[4] = {b4.x, b4.y, b4.z, b4.w};
    #pragma unroll
    for (int c = 0; c < 4; ++c)
      h[c] = fmaf((float)a4[c], h[c], bb[c]);
    *(float4*)(out + base + (size_t)t*DSZ) = make_float4(h[0], h[1], h[2], h[3]);
  }
}

extern "C" void kernel_launch(void* const* d_in, const int* in_sizes, int n_in,
                              void* d_out, int out_size, void* d_ws, size_t ws_size,
                              hipStream_t stream)
{
  const float* x  = (const float*)d_in[0];
  const float* Wz = (const float*)d_in[1];
  const float* bz = (const float*)d_in[2];
  const float* Wh = (const float*)d_in[3];
  const float* bh = (const float*)d_in[4];
  float* out = (float*)d_out;

  // ws layout: Xc (32MB) | Wzc (2MB) | Whc (2MB) | a (32MB) | Aprod|Bcomp|Hstart (2MB each)
  __bf16* Xc   = (__bf16*)d_ws;
  __bf16* Wzc  = Xc  + (size_t)MSZ * DSZ;
  __bf16* Whc  = Wzc + (size_t)DSZ * DSZ;
  __bf16* a_ws = Whc + (size_t)DSZ * DSZ;
  float* Aprod  = (float*)(a_ws + (size_t)MSZ * DSZ);
  float* Bcomp  = Aprod + (size_t)BSZ*NC*DSZ;
  float* Hstart = Bcomp + (size_t)BSZ*NC*DSZ;

  convert_tile_kernel<<<9216, 256, 0, stream>>>(x, Wz, Wh, Xc, Wzc, Whc);
  gemm_gate_kernel<<<dim3(MSZ/128, DSZ/128), 256, 0, stream>>>(
      Xc, Wzc, Whc, bz, bh, a_ws, out, Aprod, Bcomp);
  scan_pass2_kernel<<<(BSZ*DSZ)/4, 256, 0, stream>>>(Aprod, Bcomp, Hstart);
  scan_pass3_kernel<<<BSZ*NC, 256, 0, stream>>>(a_ws, Hstart, out);
}